// Round 7
// baseline (270.394 us; speedup 1.0000x reference)
//
#include <hip/hip_runtime.h>

#define NETS 32
#define BATCH 4096
#define D0 256
#define D1 512
#define D2 512
#define D3 128
#define MT 64            // batch rows per block
#define LDA (D0 + 8)     // 264 halves -> 528 B row stride
#define LDH (D1 + 8)     // 520 halves -> 1040 B row stride
#define LDO 132          // fp32 epilogue staging stride (132 mod 32 = 4 rotation)

using half8 = __attribute__((ext_vector_type(8))) _Float16;
using half4 = __attribute__((ext_vector_type(4))) _Float16;
using f32x4 = __attribute__((ext_vector_type(4))) float;

#define W1_N (NETS * D1 * D0)   // 4,194,304
#define W2_N (NETS * D2 * D1)   // 8,388,608
#define W3_N (NETS * D3 * D2)   // 2,097,152

// ---------------- fp32 -> fp16 cast + fragment swizzle ----------------
// 8-wave layout: fragment f = ((net*8 + w)*NF + kk*NI + ni), 512 halves each.
// Fragment slot l' (l' = quad*16 + lane16) owns halves [l'*8, l'*8+8) =
// W[net][n_base + ni*16 + (l'&15)][kk*32 + (l'>>4)*8 .. +8).
// Coalesced read: lane l reads row (l>>2), k-chunk (l&3)*8 -> each row's 4
// lanes cover 128 contiguous bytes (full sectors). Store permutation
// l' = ((l&3)<<4)|(l>>2) keeps the wave's store one contiguous 1-KB block.
__global__ void cvt_weights(const float* __restrict__ W1, const float* __restrict__ W2,
                            const float* __restrict__ W3,
                            _Float16* __restrict__ W1h, _Float16* __restrict__ W2h,
                            _Float16* __restrict__ W3h) {
    const int i = blockIdx.x * blockDim.x + threadIdx.x;   // one 16-B frag-slice per thread
    constexpr int T1 = W1_N / 8, T2 = W2_N / 8, T3 = W3_N / 8;
    const float* src;
    _Float16* dstf;
    int l;
    if (i < T1) {
        // L1: K=256, KK=8, NI=4, NF=32, 64 cols/wave
        int u = i; l = u & 63; int f = u >> 6;
        int ni = f & 3, kk = (f >> 2) & 7;
        int netw = f >> 5;                 // net*8 + w
        int w = netw & 7, net = netw >> 3;
        int n = w * 64 + ni * 16 + (l >> 2);
        int k = kk * 32 + (l & 3) * 8;
        src = W1 + (size_t)net * D1 * D0 + (size_t)n * D0 + k;
        dstf = W1h + (size_t)f * 512;
    } else if (i < T1 + T2) {
        // L2: K=512, KK=16, NI=4, NF=64
        int u = i - T1; l = u & 63; int f = u >> 6;
        int ni = f & 3, kk = (f >> 2) & 15;
        int netw = f >> 6;
        int w = netw & 7, net = netw >> 3;
        int n = w * 64 + ni * 16 + (l >> 2);
        int k = kk * 32 + (l & 3) * 8;
        src = W2 + (size_t)net * D2 * D1 + (size_t)n * D1 + k;
        dstf = W2h + (size_t)f * 512;
    } else {
        // L3: K=512, KK=16, NI=1, NF=16, 16 cols/wave
        int u = i - T1 - T2; l = u & 63; int f = u >> 6;
        int kk = f & 15;
        int netw = f >> 4;
        int w = netw & 7, net = netw >> 3;
        int n = w * 16 + (l >> 2);
        int k = kk * 32 + (l & 3) * 8;
        src = W3 + (size_t)net * D3 * D2 + (size_t)n * D2 + k;
        dstf = W3h + (size_t)f * 512;
    }
    float4 v0 = *reinterpret_cast<const float4*>(src);
    float4 v1 = *reinterpret_cast<const float4*>(src + 4);
    half8 o;
    o[0] = (_Float16)v0.x; o[1] = (_Float16)v0.y; o[2] = (_Float16)v0.z; o[3] = (_Float16)v0.w;
    o[4] = (_Float16)v1.x; o[5] = (_Float16)v1.y; o[6] = (_Float16)v1.z; o[7] = (_Float16)v1.w;
    const int lp = ((l & 3) << 4) | (l >> 2);          // slot permutation
    *reinterpret_cast<half8*>(dstf + lp * 8) = o;
}

// ---------------- software-pipelined layer, coalesced B stream ----------------
// G frags per step, double-buffered: prefetch distance = G*MI MFMAs.
// R6 lesson: with G=2 the distance is 145 cy < L2 latency -> TLP gains eaten
// by per-step stalls. G=4 restores 290 cy (R0's distance) and fits the
// 128-reg cap: acc 64 + B 32 + A 16 + addr ~14.
template<int K, int NI, int G, int MI>
__device__ __forceinline__ void layer_mfma(const _Float16* As, int lda,
                                           const _Float16* __restrict__ wl,
                                           int lane16, int quad,
                                           f32x4 (&acc)[MI][NI]) {
    constexpr int NFR = (K / 32) * NI;
    constexpr int STEPS = NFR / G;
    half8 bcur[G], bnxt[G];
    half8 a[MI];
#pragma unroll
    for (int g = 0; g < G; ++g)
        bcur[g] = *reinterpret_cast<const half8*>(wl + (size_t)g * 512);
#pragma unroll
    for (int s = 0; s < STEPS; ++s) {
        const int fb = s * G;
        if (s + 1 < STEPS) {
#pragma unroll
            for (int g = 0; g < G; ++g)
                bnxt[g] = *reinterpret_cast<const half8*>(wl + (size_t)(fb + G + g) * 512);
        }
        if (fb % NI == 0) {
            const int kk = fb / NI;
#pragma unroll
            for (int mi = 0; mi < MI; ++mi)
                a[mi] = *reinterpret_cast<const half8*>(
                    As + (mi * 16 + lane16) * lda + kk * 32 + quad * 8);
        }
#pragma unroll
        for (int g = 0; g < G; ++g) {
            const int ni = (fb + g) % NI;
#pragma unroll
            for (int mi = 0; mi < MI; ++mi)
                acc[mi][ni] = __builtin_amdgcn_mfma_f32_16x16x32_f16(a[mi], bcur[g], acc[mi][ni], 0, 0, 0);
        }
        if (s + 1 < STEPS) {
#pragma unroll
            for (int g = 0; g < G; ++g) bcur[g] = bnxt[g];
        }
    }
}

template<int MI, int NI>
__device__ __forceinline__ void store_act(f32x4 (&acc)[MI][NI], const float* __restrict__ bias,
                                          _Float16* dst, int ldd, int n_base,
                                          int lane16, int quad) {
#pragma unroll
    for (int ni = 0; ni < NI; ++ni) {
        float bv = bias[n_base + ni * 16 + lane16];
        int col = n_base + ni * 16 + lane16;
#pragma unroll
        for (int mi = 0; mi < MI; ++mi) {
#pragma unroll
            for (int r = 0; r < 4; ++r) {
                float v = acc[mi][ni][r] + bv;
                v = fmaxf(v, 0.0f);                        // relu
                int row = mi * 16 + quad * 4 + r;
                dst[row * ldd + col] = (_Float16)v;
            }
        }
    }
}

// ---------------- fused 3-layer MLP, 8 waves/block, 4 waves/SIMD ----------------
// 64-row x full-N tile, 65-KB LDS -> 2 blocks/CU x 8 waves = 4 waves/SIMD.
// Wave owns 64x64 (acc[4][4] = 64 AGPR), G=4 B-double-buffer (32 VGPR).
__global__ __launch_bounds__(512, 4) void mlp_fused(
    const float* __restrict__ X,
    const _Float16* __restrict__ W1h, const float* __restrict__ b1,
    const _Float16* __restrict__ W2h, const float* __restrict__ b2,
    const _Float16* __restrict__ W3h, const float* __restrict__ b3,
    float* __restrict__ out) {
    __shared__ __align__(16) _Float16 buf[MT * LDH];   // X (LDA) -> H1 -> H2 (LDH) -> fp32 out stage

    const int tid = threadIdx.x;
    const int w = tid >> 6;               // 0..7
    const int l = tid & 63;
    const int lane16 = l & 15;
    const int quad = l >> 4;

    // XCD-locality: dispatch round-robins blockIdx over 8 XCDs -> 4 nets/XCD.
    const int bb = blockIdx.x;            // 0..2047
    const int xcd = bb & 7;
    const int s = bb >> 3;                // 0..255
    const int net = xcd * 4 + (s >> 6);   // 0..31
    const int mt = s & 63;                // 0..63
    const int m0 = mt * MT;

    // ---- stage X tile [MT][D0] fp32 -> fp16 into buf (LDA layout) ----
    {
        const float* xsrc = X + (size_t)m0 * D0;
#pragma unroll
        for (int it = 0; it < 8; ++it) {
            int chunk = it * 512 + tid;   // 0..4095; 64 float4 per row
            int row = chunk >> 6;
            int c4 = chunk & 63;
            float4 v = *reinterpret_cast<const float4*>(xsrc + row * D0 + c4 * 4);
            half4 o;
            o[0] = (_Float16)v.x; o[1] = (_Float16)v.y;
            o[2] = (_Float16)v.z; o[3] = (_Float16)v.w;
            *reinterpret_cast<half4*>(&buf[row * LDA + c4 * 4]) = o;
        }
    }
    __syncthreads();

    // ---- layer 1: H1 = relu(X @ W1^T + b1), K=256, N=512 (wave owns 64 cols) ----
    {
        f32x4 acc[4][4] = {};
        const _Float16* wl = W1h + ((size_t)(net * 8 + w) * 32) * 512 + l * 8;
        layer_mfma<D0, 4, 4, 4>(buf, LDA, wl, lane16, quad, acc);
        __syncthreads();                               // all X reads done
        store_act<4, 4>(acc, b1 + net * D1, buf, LDH, w * 64, lane16, quad);
    }
    __syncthreads();

    // ---- layer 2: H2 = relu(H1 @ W2^T + b2), K=512, N=512 ----
    {
        f32x4 acc[4][4] = {};
        const _Float16* wl = W2h + ((size_t)(net * 8 + w) * 64) * 512 + l * 8;
        layer_mfma<D1, 4, 4, 4>(buf, LDH, wl, lane16, quad, acc);
        __syncthreads();                               // all H1 reads done
        store_act<4, 4>(acc, b2 + net * D2, buf, LDH, w * 64, lane16, quad);
    }
    __syncthreads();

    // ---- layer 3: out = H2 @ W3^T + b3, K=512, N=128 (wave owns 16 cols) ----
    // Staged epilogue (R6 write-amp fix): acc -> LDS fp32 -> cooperative
    // float4 stores where 32 consecutive lanes cover 512 contiguous bytes
    // per out row -> every 128-B line fully written by one instruction burst.
    {
        f32x4 acc[4][1] = {};
        const _Float16* wl = W3h + ((size_t)(net * 8 + w) * 16) * 512 + l * 8;
        layer_mfma<D2, 1, 1, 4>(buf, LDH, wl, lane16, quad, acc);
        __syncthreads();                               // all H2 reads done
        float* buff = reinterpret_cast<float*>(buf);   // reuse as [64][LDO] fp32
        const int n_base = w * 16;
        const float bv = b3[net * D3 + n_base + lane16];
#pragma unroll
        for (int mi = 0; mi < 4; ++mi) {
#pragma unroll
            for (int r = 0; r < 4; ++r) {
                int row = mi * 16 + quad * 4 + r;
                buff[row * LDO + n_base + lane16] = acc[mi][0][r] + bv;
            }
        }
        __syncthreads();
        // 64 rows x 128 floats = 2048 float4; 512 threads x 4.
#pragma unroll
        for (int it = 0; it < 4; ++it) {
            int idx = it * 512 + tid;                  // 32 float4 per row
            int row = idx >> 5;
            int c4 = idx & 31;
            f32x4 v = *reinterpret_cast<const f32x4*>(&buff[row * LDO + c4 * 4]);
            *reinterpret_cast<f32x4*>(
                &out[(size_t)(m0 + row) * (NETS * D3) + net * D3 + c4 * 4]) = v;
        }
    }
}

extern "C" void kernel_launch(void* const* d_in, const int* in_sizes, int n_in,
                              void* d_out, int out_size, void* d_ws, size_t ws_size,
                              hipStream_t stream) {
    const float* x  = (const float*)d_in[0];
    const float* W1 = (const float*)d_in[1];
    const float* b1 = (const float*)d_in[2];
    const float* W2 = (const float*)d_in[3];
    const float* b2 = (const float*)d_in[4];
    const float* W3 = (const float*)d_in[5];
    const float* b3 = (const float*)d_in[6];
    float* out = (float*)d_out;

    // ws layout (fp16, swizzled): W1h | W2h | W3h  = ~29.4 MB total
    _Float16* W1h = (_Float16*)d_ws;
    _Float16* W2h = W1h + (size_t)W1_N;
    _Float16* W3h = W2h + (size_t)W2_N;

    const int totalT = (W1_N + W2_N + W3_N) / 8;       // 1,835,008 threads
    cvt_weights<<<totalT / 256, 256, 0, stream>>>(W1, W2, W3, W1h, W2h, W3h);

    mlp_fused<<<NETS * (BATCH / MT), 512, 0, stream>>>(x, W1h, b1, W2h, b2, W3h, b3, out);
}